// Round 2
// baseline (85.780 us; speedup 1.0000x reference)
//
#include <hip/hip_runtime.h>

// L[b] = -i*(H kron I - I kron H^T) + DECAY
// H real symmetric 4x4: H = Om*Hd - D1*N1 - D2*N2 + V*Nrr
//   off-diag: 0.5*Om iff (x^y)==1 or (x^y)==2; diag(H) = {0, -D2, -D1, -D1-D2+V}
// DECAY (batch-independent, REAL):
//   diag[r] = -0.5*g*((i>>1)+(i&1)+(j>>1)+(j&1)), i=r>>2, j=r&3
//   +g at (i<2 && j<2 && k==i+2 && l==j+2)   [c1 (x) c1]
//   +g at (i,j even && k==i+1 && l==j+1)     [c2 (x) c2]
//
// ROUND 1 LESSON: never write more than out_size floats — round 1 wrote
// B*512 floats unconditionally and aborted the harness (buffer overrun).
// Layout is now chosen from out_size/B at launch time.

#define GAMMA_F 11363.636363636364f   // 1 / 88e-6

__device__ __forceinline__ float Hxy(int x, int y, float om2, float D1, float D2, float V) {
    if (x == y) {
        float d = 0.0f;
        if (x & 2) d -= D1;
        if (x & 1) d -= D2;
        if (x == 3) d += V;
        return d;
    }
    int t = x ^ y;
    return (t == 1 || t == 2) ? om2 : 0.0f;
}

__device__ __forceinline__ float decay_rc(int r, int c) {
    int i = r >> 2, j = r & 3, k = c >> 2, l = c & 3;
    float d = 0.0f;
    if (r == c)
        d = -0.5f * GAMMA_F * (float)((i >> 1) + (i & 1) + (j >> 1) + (j & 1));
    if (i < 2 && j < 2 && k == i + 2 && l == j + 2) d += GAMMA_F;      // c1 (x) c1
    if (!(i & 1) && !(j & 1) && k == i + 1 && l == j + 1) d += GAMMA_F; // c2 (x) c2
    return d;
}

// Layout A: out_size == B*512 -> interleaved (re,im) float32; 128 float4/batch.
__global__ __launch_bounds__(256) void lindblad_cplx(
        const float* __restrict__ Om, const float* __restrict__ De,
        const float* __restrict__ dd1, const float* __restrict__ dd2,
        const float* __restrict__ dph, const float* __restrict__ Vv,
        float4* __restrict__ out, int n4) {
    int g = blockIdx.x * blockDim.x + threadIdx.x;  // one float4 = 2 complex elems
    if (g >= n4) return;
    int b = g >> 7;
    int e = g & 127;

    float om2 = 0.5f * Om[b];
    float dp  = dph[b];
    float dl  = De[b];
    float D1  = dl + dd1[b] + dp;
    float D2  = dl + dd2[b] + dp;
    float V   = Vv[b];

    int r  = e >> 3;          // row in 16x16
    int c0 = (e & 7) << 1;    // first of two adjacent cols
    int i = r >> 2, j = r & 3;

    float4 o;
    {
        int c = c0, k = c >> 2, l = c & 3;
        float im = 0.0f;
        if (j == l) im -= Hxy(i, k, om2, D1, D2, V);
        if (i == k) im += Hxy(j, l, om2, D1, D2, V);
        o.x = decay_rc(r, c);
        o.y = im;
    }
    {
        int c = c0 + 1, k = c >> 2, l = c & 3;
        float im = 0.0f;
        if (j == l) im -= Hxy(i, k, om2, D1, D2, V);
        if (i == k) im += Hxy(j, l, om2, D1, D2, V);
        o.z = decay_rc(r, c);
        o.w = im;
    }
    out[g] = o;
}

// Layout B: out_size == B*256 -> one float32 per complex element (real part
// only = batch-independent DECAY). 64 float4 per batch row-major.
__global__ __launch_bounds__(256) void lindblad_real(
        float4* __restrict__ out, int n4) {
    int g = blockIdx.x * blockDim.x + threadIdx.x;  // one float4 = 4 real elems
    if (g >= n4) return;
    int e = g & 63;           // element within batch (float4 units)
    int r = e >> 2;           // row in 16x16
    int c0 = (e & 3) << 2;    // first of four cols
    float4 o;
    o.x = decay_rc(r, c0 + 0);
    o.y = decay_rc(r, c0 + 1);
    o.z = decay_rc(r, c0 + 2);
    o.w = decay_rc(r, c0 + 3);
    out[g] = o;
}

extern "C" void kernel_launch(void* const* d_in, const int* in_sizes, int n_in,
                              void* d_out, int out_size, void* d_ws, size_t ws_size,
                              hipStream_t stream) {
    const float* Om  = (const float*)d_in[0];
    const float* De  = (const float*)d_in[1];
    const float* dd1 = (const float*)d_in[2];
    const float* dd2 = (const float*)d_in[3];
    const float* dph = (const float*)d_in[4];
    const float* dVv = (const float*)d_in[5];
    int B = in_sizes[0];

    const int block = 256;

    if (out_size == B * 256) {
        // real-only layout: exactly out_size floats = out_size/4 float4s
        int n4 = out_size >> 2;
        int grid = (n4 + block - 1) / block;
        lindblad_real<<<grid, block, 0, stream>>>((float4*)d_out, n4);
    } else {
        // interleaved (re,im) layout, bounds-checked to never exceed out_size
        int n4 = out_size >> 2;               // total float4 capacity of d_out
        int want4 = B * 128;                  // what the full complex matrix needs
        if (n4 > want4) n4 = want4;
        int grid = (n4 + block - 1) / block;
        lindblad_cplx<<<grid, block, 0, stream>>>(Om, De, dd1, dd2, dph, dVv,
                                                  (float4*)d_out, n4);
    }
}